// Round 2
// baseline (45.023 us; speedup 1.0000x reference)
//
#include <hip/hip_runtime.h>

#define X_DIM 5
#define Y_DIM 2
#define H1 560
#define H2 40
#define GRUH 145

__device__ __forceinline__ float wave_reduce(float v) {
#pragma unroll
    for (int off = 32; off > 0; off >>= 1)
        v += __shfl_xor(v, off, 64);
    return v;
}

__device__ __forceinline__ float sigmoidf_(float x) {
    return 1.0f / (1.0f + __expf(-x));
}

// One persistent kernel: 145 blocks x 256 threads (all co-resident; 145 < 256 CUs).
// Block i owns GRU element i of both layers.
//  Stage AB: redundant x+l1 in LDS; gi0/gh0 dots -> h0[i] (global);
//            gh1 rows {i,i+145,i+290} -> LDS (consumed by the same block later).
//  Grid barrier (device-scope atomics in ws, zeroed by memsetAsync each call).
//  Stage C: h1[i] from h0(LDS-staged) + cached gh1 -> global; last block to
//           finish runs the l2 head and writes d_out.
__global__ __launch_bounds__(256) void fused_kalmannet(
    const float* __restrict__ si, const float* __restrict__ oi,
    const float* __restrict__ dst, const float* __restrict__ dob,
    const float* __restrict__ W1, const float* __restrict__ b1,
    const float* __restrict__ Wih0, const float* __restrict__ Whh0,
    const float* __restrict__ bih0, const float* __restrict__ bhh0,
    const float* __restrict__ Wih1, const float* __restrict__ Whh1,
    const float* __restrict__ bih1, const float* __restrict__ bhh1,
    const float* __restrict__ W2a, const float* __restrict__ b2a,
    const float* __restrict__ W2b, const float* __restrict__ b2b,
    const float* __restrict__ hn,
    unsigned* __restrict__ ctr,          // [0]=barrier arrive, [1]=doneC
    float* __restrict__ h0g, float* __restrict__ h1g,
    float* __restrict__ out)
{
    __shared__ float sx[16];
    __shared__ float sl1[H1];
    __shared__ float sred[4][9];
    __shared__ float sh[GRUH + 15];   // h0 in stage C, h1 in stage D
    __shared__ float sgh1[3];
    __shared__ float sl2h[H2];
    __shared__ unsigned slast;

    const int tid = threadIdx.x;
    const int wid = tid >> 6, lane = tid & 63;
    const int i = blockIdx.x;            // 0..144: GRU element index

    // ---- x into LDS ----
    if (tid < X_DIM)                      sx[tid] = si[tid];
    else if (tid < X_DIM + Y_DIM)         sx[tid] = oi[tid - X_DIM];
    else if (tid < 2 * X_DIM + Y_DIM)     sx[tid] = dst[tid - X_DIM - Y_DIM];
    else if (tid < 2 * X_DIM + 2 * Y_DIM) sx[tid] = dob[tid - 2 * X_DIM - Y_DIM];
    __syncthreads();

    // ---- l1 = relu(W1 @ x + b1), redundant per block ----
    for (int j = tid; j < H1; j += 256) {
        float a = b1[j];
        const float* w = W1 + j * 14;
#pragma unroll
        for (int k = 0; k < 14; ++k) a = fmaf(w[k], sx[k], a);
        sl1[j] = fmaxf(a, 0.0f);
    }
    __syncthreads();

    // ---- stage AB dots: gi0 (3x560), gh0 (3x145), gh1 rows (3x145) ----
    float a0 = 0.f, a1 = 0.f, a2 = 0.f;
    for (int k = tid; k < H1; k += 256) {
        const float lv = sl1[k];
        a0 = fmaf(Wih0[(i           ) * H1 + k], lv, a0);
        a1 = fmaf(Wih0[(i +   GRUH  ) * H1 + k], lv, a1);
        a2 = fmaf(Wih0[(i + 2 * GRUH) * H1 + k], lv, a2);
    }
    float a3 = 0.f, a4 = 0.f, a5 = 0.f, a6 = 0.f, a7 = 0.f, a8 = 0.f;
    for (int k = tid; k < GRUH; k += 256) {
        const float h0v = hn[k];
        const float h1v = hn[GRUH + k];
        a3 = fmaf(Whh0[(i           ) * GRUH + k], h0v, a3);
        a4 = fmaf(Whh0[(i +   GRUH  ) * GRUH + k], h0v, a4);
        a5 = fmaf(Whh0[(i + 2 * GRUH) * GRUH + k], h0v, a5);
        a6 = fmaf(Whh1[(i           ) * GRUH + k], h1v, a6);
        a7 = fmaf(Whh1[(i +   GRUH  ) * GRUH + k], h1v, a7);
        a8 = fmaf(Whh1[(i + 2 * GRUH) * GRUH + k], h1v, a8);
    }
    a0 = wave_reduce(a0); a1 = wave_reduce(a1); a2 = wave_reduce(a2);
    a3 = wave_reduce(a3); a4 = wave_reduce(a4); a5 = wave_reduce(a5);
    a6 = wave_reduce(a6); a7 = wave_reduce(a7); a8 = wave_reduce(a8);
    if (lane == 0) {
        sred[wid][0] = a0; sred[wid][1] = a1; sred[wid][2] = a2;
        sred[wid][3] = a3; sred[wid][4] = a4; sred[wid][5] = a5;
        sred[wid][6] = a6; sred[wid][7] = a7; sred[wid][8] = a8;
    }
    __syncthreads();
    if (tid == 0) {
        float v[9];
#pragma unroll
        for (int q = 0; q < 9; ++q)
            v[q] = sred[0][q] + sred[1][q] + sred[2][q] + sred[3][q];
        const float r = sigmoidf_(v[0] + bih0[i]            + v[3] + bhh0[i]);
        const float z = sigmoidf_(v[1] + bih0[i + GRUH]     + v[4] + bhh0[i + GRUH]);
        const float n = tanhf   (v[2] + bih0[i + 2 * GRUH] + r * (v[5] + bhh0[i + 2 * GRUH]));
        h0g[i] = (1.0f - z) * n + z * hn[i];
        sgh1[0] = v[6] + bhh1[i];
        sgh1[1] = v[7] + bhh1[i + GRUH];
        sgh1[2] = v[8] + bhh1[i + 2 * GRUH];
    }

    // ---- grid barrier (all 145 blocks) ----
    __syncthreads();
    if (tid == 0) {
        __threadfence();   // publish h0g[i]
        __hip_atomic_fetch_add(&ctr[0], 1u, __ATOMIC_ACQ_REL, __HIP_MEMORY_SCOPE_AGENT);
        while (__hip_atomic_load(&ctr[0], __ATOMIC_ACQUIRE, __HIP_MEMORY_SCOPE_AGENT) < 145u)
            __builtin_amdgcn_s_sleep(1);
    }
    __syncthreads();
    __threadfence();       // acquire for all threads

    // ---- stage C: h1[i] ----
    if (tid < GRUH) sh[tid] = h0g[tid];
    __syncthreads();
    float c0 = 0.f, c1 = 0.f, c2 = 0.f;
    for (int k = tid; k < GRUH; k += 256) {
        const float hv = sh[k];
        c0 = fmaf(Wih1[(i           ) * GRUH + k], hv, c0);
        c1 = fmaf(Wih1[(i +   GRUH  ) * GRUH + k], hv, c1);
        c2 = fmaf(Wih1[(i + 2 * GRUH) * GRUH + k], hv, c2);
    }
    c0 = wave_reduce(c0); c1 = wave_reduce(c1); c2 = wave_reduce(c2);
    if (lane == 0) {
        sred[wid][0] = c0; sred[wid][1] = c1; sred[wid][2] = c2;
    }
    __syncthreads();
    if (tid == 0) {
        const float ir  = sred[0][0] + sred[1][0] + sred[2][0] + sred[3][0] + bih1[i];
        const float iz  = sred[0][1] + sred[1][1] + sred[2][1] + sred[3][1] + bih1[i + GRUH];
        const float in_ = sred[0][2] + sred[1][2] + sred[2][2] + sred[3][2] + bih1[i + 2 * GRUH];
        const float r = sigmoidf_(ir + sgh1[0]);
        const float z = sigmoidf_(iz + sgh1[1]);
        const float n = tanhf(in_ + r * sgh1[2]);
        h1g[i] = (1.0f - z) * n + z * hn[GRUH + i];
        __threadfence();   // publish h1g[i]
        const unsigned old =
            __hip_atomic_fetch_add(&ctr[1], 1u, __ATOMIC_ACQ_REL, __HIP_MEMORY_SCOPE_AGENT);
        slast = (old == 144u) ? 1u : 0u;
    }
    __syncthreads();
    if (!slast) return;

    // ---- stage D (last block only): l2 head ----
    __threadfence();       // acquire h1g written by other blocks
    if (tid < GRUH) sh[tid] = h1g[tid];
    __syncthreads();
    for (int row = wid; row < H2; row += 4) {
        float a = 0.f;
        for (int k = lane; k < GRUH; k += 64)
            a = fmaf(W2a[row * GRUH + k], sh[k], a);
        a = wave_reduce(a);
        if (lane == 0) sl2h[row] = fmaxf(a + b2a[row], 0.0f);
    }
    __syncthreads();
    if (tid < X_DIM * Y_DIM) {
        float a = b2b[tid];
#pragma unroll
        for (int k = 0; k < H2; ++k)
            a = fmaf(W2b[tid * H2 + k], sl2h[k], a);
        out[tid] = a;
    }
}

extern "C" void kernel_launch(void* const* d_in, const int* in_sizes, int n_in,
                              void* d_out, int out_size, void* d_ws, size_t ws_size,
                              hipStream_t stream) {
    const float* si   = (const float*)d_in[0];
    const float* oi   = (const float*)d_in[1];
    const float* dst  = (const float*)d_in[2];
    const float* dob  = (const float*)d_in[3];
    const float* W1   = (const float*)d_in[4];
    const float* b1   = (const float*)d_in[5];
    const float* Wih0 = (const float*)d_in[6];
    const float* Whh0 = (const float*)d_in[7];
    const float* bih0 = (const float*)d_in[8];
    const float* bhh0 = (const float*)d_in[9];
    const float* Wih1 = (const float*)d_in[10];
    const float* Whh1 = (const float*)d_in[11];
    const float* bih1 = (const float*)d_in[12];
    const float* bhh1 = (const float*)d_in[13];
    const float* W2a  = (const float*)d_in[14];
    const float* b2a  = (const float*)d_in[15];
    const float* W2b  = (const float*)d_in[16];
    const float* b2b  = (const float*)d_in[17];
    const float* hn   = (const float*)d_in[18];

    float* ws = (float*)d_ws;
    unsigned* ctr = (unsigned*)d_ws;     // ws[0..1]: barrier + done counters
    float* h0g = ws + 64;                // 145 floats
    float* h1g = ws + 64 + 256;          // 145 floats

    // Zero the two counters every call (replay-deterministic).
    hipMemsetAsync(ctr, 0, 2 * sizeof(unsigned), stream);

    hipLaunchKernelGGL(fused_kalmannet, dim3(GRUH), dim3(256), 0, stream,
                       si, oi, dst, dob, W1, b1, Wih0, Whh0, bih0, bhh0,
                       Wih1, Whh1, bih1, bhh1, W2a, b2a, W2b, b2b, hn,
                       ctr, h0g, h1g, (float*)d_out);
}

// Round 3
// 39.111 us; speedup vs baseline: 1.1511x; 1.1511x over previous
//
#include <hip/hip_runtime.h>

#define X_DIM 5
#define Y_DIM 2
#define H1 560
#define H2 40
#define GRUH 145
#define NBLK 37          // 37 blocks x 4 elements = 148 >= 145

__device__ __forceinline__ float wave_reduce(float v) {
#pragma unroll
    for (int off = 32; off > 0; off >>= 1)
        v += __shfl_xor(v, off, 64);
    return v;
}

__device__ __forceinline__ float sigmoidf_(float x) {
    return 1.0f / (1.0f + __expf(-x));
}

// One persistent kernel: 37 blocks x 1024 threads. Block b, 256-thread group g
// owns GRU element e = 4b+g (e<145). Stage AB: redundant x+l1 in LDS; gi0/gh0
// dots -> h0g[e]; gh1 rows {e,e+145,e+290} cached in LDS. Flag-based grid
// barrier (counter and flag on separate cache lines, s_sleep backoff).
// Stage C: h1[e]. Last block to finish stage C runs the l2 head.
__global__ __launch_bounds__(1024) void fused_kalmannet(
    const float* __restrict__ si, const float* __restrict__ oi,
    const float* __restrict__ dst, const float* __restrict__ dob,
    const float* __restrict__ W1, const float* __restrict__ b1,
    const float* __restrict__ Wih0, const float* __restrict__ Whh0,
    const float* __restrict__ bih0, const float* __restrict__ bhh0,
    const float* __restrict__ Wih1, const float* __restrict__ Whh1,
    const float* __restrict__ bih1, const float* __restrict__ bhh1,
    const float* __restrict__ W2a, const float* __restrict__ b2a,
    const float* __restrict__ W2b, const float* __restrict__ b2b,
    const float* __restrict__ hn,
    unsigned* __restrict__ ctr,   // [0]=arrive, [16]=flag, [32]=doneC (separate lines)
    float* __restrict__ h0g, float* __restrict__ h1g,
    float* __restrict__ out)
{
    __shared__ float sx[16];
    __shared__ float sl1[H1];
    __shared__ float sred[4][4][9];   // [group][wave-in-group][dot]
    __shared__ float sh[GRUH + 15];
    __shared__ float sgh1[4][3];
    __shared__ float sl2h[H2];
    __shared__ unsigned slast;

    const int tid  = threadIdx.x;
    const int g    = tid >> 8;        // 256-thread group 0..3
    const int t    = tid & 255;       // index within group
    const int w    = (tid >> 6) & 3;  // wave within group
    const int lane = tid & 63;
    const int e    = blockIdx.x * 4 + g;   // GRU element
    const bool act = (e < GRUH);

    // ---- x into LDS ----
    if (tid < X_DIM)                      sx[tid] = si[tid];
    else if (tid < X_DIM + Y_DIM)         sx[tid] = oi[tid - X_DIM];
    else if (tid < 2 * X_DIM + Y_DIM)     sx[tid] = dst[tid - X_DIM - Y_DIM];
    else if (tid < 2 * X_DIM + 2 * Y_DIM) sx[tid] = dob[tid - 2 * X_DIM - Y_DIM];
    __syncthreads();

    // ---- l1 = relu(W1 @ x + b1), redundant per block ----
    for (int j = tid; j < H1; j += 1024) {
        float a = b1[j];
        const float* wp = W1 + j * 14;
#pragma unroll
        for (int k = 0; k < 14; ++k) a = fmaf(wp[k], sx[k], a);
        sl1[j] = fmaxf(a, 0.0f);
    }
    __syncthreads();

    // ---- stage AB dots: gi0 (3x560), gh0 (3x145), gh1 rows (3x145) ----
    float a0 = 0.f, a1 = 0.f, a2 = 0.f;
    float a3 = 0.f, a4 = 0.f, a5 = 0.f, a6 = 0.f, a7 = 0.f, a8 = 0.f;
    if (act) {
        for (int k = t; k < H1; k += 256) {
            const float lv = sl1[k];
            a0 = fmaf(Wih0[(e           ) * H1 + k], lv, a0);
            a1 = fmaf(Wih0[(e +   GRUH  ) * H1 + k], lv, a1);
            a2 = fmaf(Wih0[(e + 2 * GRUH) * H1 + k], lv, a2);
        }
        for (int k = t; k < GRUH; k += 256) {
            const float h0v = hn[k];
            const float h1v = hn[GRUH + k];
            a3 = fmaf(Whh0[(e           ) * GRUH + k], h0v, a3);
            a4 = fmaf(Whh0[(e +   GRUH  ) * GRUH + k], h0v, a4);
            a5 = fmaf(Whh0[(e + 2 * GRUH) * GRUH + k], h0v, a5);
            a6 = fmaf(Whh1[(e           ) * GRUH + k], h1v, a6);
            a7 = fmaf(Whh1[(e +   GRUH  ) * GRUH + k], h1v, a7);
            a8 = fmaf(Whh1[(e + 2 * GRUH) * GRUH + k], h1v, a8);
        }
    }
    a0 = wave_reduce(a0); a1 = wave_reduce(a1); a2 = wave_reduce(a2);
    a3 = wave_reduce(a3); a4 = wave_reduce(a4); a5 = wave_reduce(a5);
    a6 = wave_reduce(a6); a7 = wave_reduce(a7); a8 = wave_reduce(a8);
    if (lane == 0) {
        sred[g][w][0] = a0; sred[g][w][1] = a1; sred[g][w][2] = a2;
        sred[g][w][3] = a3; sred[g][w][4] = a4; sred[g][w][5] = a5;
        sred[g][w][6] = a6; sred[g][w][7] = a7; sred[g][w][8] = a8;
    }
    __syncthreads();
    if (t == 0 && act) {
        float v[9];
#pragma unroll
        for (int q = 0; q < 9; ++q)
            v[q] = sred[g][0][q] + sred[g][1][q] + sred[g][2][q] + sred[g][3][q];
        const float r = sigmoidf_(v[0] + bih0[e]            + v[3] + bhh0[e]);
        const float z = sigmoidf_(v[1] + bih0[e + GRUH]     + v[4] + bhh0[e + GRUH]);
        const float n = tanhf   (v[2] + bih0[e + 2 * GRUH] + r * (v[5] + bhh0[e + 2 * GRUH]));
        h0g[e] = (1.0f - z) * n + z * hn[e];
        sgh1[g][0] = v[6] + bhh1[e];
        sgh1[g][1] = v[7] + bhh1[e + GRUH];
        sgh1[g][2] = v[8] + bhh1[e + 2 * GRUH];
    }

    // ---- grid barrier: counter on line 0, flag on line 1, poll flag only ----
    __syncthreads();
    if (tid == 0) {
        __threadfence();   // publish h0g[e]
        const unsigned old =
            __hip_atomic_fetch_add(&ctr[0], 1u, __ATOMIC_ACQ_REL, __HIP_MEMORY_SCOPE_AGENT);
        if (old == NBLK - 1u)
            __hip_atomic_store(&ctr[16], 1u, __ATOMIC_RELEASE, __HIP_MEMORY_SCOPE_AGENT);
        while (__hip_atomic_load(&ctr[16], __ATOMIC_ACQUIRE, __HIP_MEMORY_SCOPE_AGENT) == 0u)
            __builtin_amdgcn_s_sleep(32);
        __threadfence();
    }
    __syncthreads();
    __threadfence();       // acquire for all threads

    // ---- stage C: h1[e] ----
    if (tid < GRUH) sh[tid] = h0g[tid];
    __syncthreads();
    float c0 = 0.f, c1 = 0.f, c2 = 0.f;
    if (act) {
        for (int k = t; k < GRUH; k += 256) {
            const float hv = sh[k];
            c0 = fmaf(Wih1[(e           ) * GRUH + k], hv, c0);
            c1 = fmaf(Wih1[(e +   GRUH  ) * GRUH + k], hv, c1);
            c2 = fmaf(Wih1[(e + 2 * GRUH) * GRUH + k], hv, c2);
        }
    }
    c0 = wave_reduce(c0); c1 = wave_reduce(c1); c2 = wave_reduce(c2);
    if (lane == 0) {
        sred[g][w][0] = c0; sred[g][w][1] = c1; sred[g][w][2] = c2;
    }
    __syncthreads();
    if (t == 0 && act) {
        const float ir  = sred[g][0][0] + sred[g][1][0] + sred[g][2][0] + sred[g][3][0] + bih1[e];
        const float iz  = sred[g][0][1] + sred[g][1][1] + sred[g][2][1] + sred[g][3][1] + bih1[e + GRUH];
        const float in_ = sred[g][0][2] + sred[g][1][2] + sred[g][2][2] + sred[g][3][2] + bih1[e + 2 * GRUH];
        const float r = sigmoidf_(ir + sgh1[g][0]);
        const float z = sigmoidf_(iz + sgh1[g][1]);
        const float n = tanhf(in_ + r * sgh1[g][2]);
        h1g[e] = (1.0f - z) * n + z * hn[GRUH + e];
    }
    __syncthreads();
    if (tid == 0) {
        __threadfence();   // publish h1g
        const unsigned old =
            __hip_atomic_fetch_add(&ctr[32], 1u, __ATOMIC_ACQ_REL, __HIP_MEMORY_SCOPE_AGENT);
        slast = (old == NBLK - 1u) ? 1u : 0u;
    }
    __syncthreads();
    if (!slast) return;

    // ---- stage D (last-finishing block only): l2 head ----
    __threadfence();       // acquire h1g written by other blocks
    if (tid < GRUH) sh[tid] = h1g[tid];
    __syncthreads();
    const int wv = tid >> 6;   // 0..15
    for (int row = wv; row < H2; row += 16) {
        float a = 0.f;
        for (int k = lane; k < GRUH; k += 64)
            a = fmaf(W2a[row * GRUH + k], sh[k], a);
        a = wave_reduce(a);
        if (lane == 0) sl2h[row] = fmaxf(a + b2a[row], 0.0f);
    }
    __syncthreads();
    if (tid < X_DIM * Y_DIM) {
        float a = b2b[tid];
#pragma unroll
        for (int k = 0; k < H2; ++k)
            a = fmaf(W2b[tid * H2 + k], sl2h[k], a);
        out[tid] = a;
    }
}

extern "C" void kernel_launch(void* const* d_in, const int* in_sizes, int n_in,
                              void* d_out, int out_size, void* d_ws, size_t ws_size,
                              hipStream_t stream) {
    const float* si   = (const float*)d_in[0];
    const float* oi   = (const float*)d_in[1];
    const float* dst  = (const float*)d_in[2];
    const float* dob  = (const float*)d_in[3];
    const float* W1   = (const float*)d_in[4];
    const float* b1   = (const float*)d_in[5];
    const float* Wih0 = (const float*)d_in[6];
    const float* Whh0 = (const float*)d_in[7];
    const float* bih0 = (const float*)d_in[8];
    const float* bhh0 = (const float*)d_in[9];
    const float* Wih1 = (const float*)d_in[10];
    const float* Whh1 = (const float*)d_in[11];
    const float* bih1 = (const float*)d_in[12];
    const float* bhh1 = (const float*)d_in[13];
    const float* W2a  = (const float*)d_in[14];
    const float* b2a  = (const float*)d_in[15];
    const float* W2b  = (const float*)d_in[16];
    const float* b2b  = (const float*)d_in[17];
    const float* hn   = (const float*)d_in[18];

    float* ws = (float*)d_ws;
    unsigned* ctr = (unsigned*)d_ws;     // uses indices 0,16,32 (3 cache lines)
    float* h0g = ws + 64;                // 145 floats
    float* h1g = ws + 64 + 256;          // 145 floats

    // Zero the counters/flag every call (replay-deterministic).
    hipMemsetAsync(ctr, 0, 33 * sizeof(unsigned), stream);

    hipLaunchKernelGGL(fused_kalmannet, dim3(NBLK), dim3(1024), 0, stream,
                       si, oi, dst, dob, W1, b1, Wih0, Whh0, bih0, bhh0,
                       Wih1, Whh1, bih1, bhh1, W2a, b2a, W2b, b2b, hn,
                       ctr, h0g, h1g, (float*)d_out);
}